// Round 5
// baseline (279.629 us; speedup 1.0000x reference)
//
#include <hip/hip_runtime.h>
#include <hip/hip_bf16.h>

// ---------------- problem constants ----------------
// B=2 T2=9 T3=27 T1=243 P=17 K2=9 C=128
// CH = {48,96,192,384}, HW = {(96,72),(48,36),(24,18),(12,9)}, N=18
static constexpr int NQ_SIZE = 9517824;
static constexpr int NV_SIZE = 1057536;

// E-map (projected feature, bf16, channels-last [n,h,w,128]) element offsets in ws
static constexpr long E0_OFF = 0;
static constexpr long E1_OFF = 15925248;            // 18*96*72*128
static constexpr long E2_OFF = E1_OFF + 3981312;    // 18*48*36*128
static constexpr long E3_OFF = E2_OFF + 995328;     // 18*24*18*128
static constexpr long E_END  = E3_OFF + 248832;     // 18*12*9*128  -> 21,150,720 elems

// prep kernel block-range segmentation (long-serial levels first)
static constexpr int SEG_F3  = 36;            // 2 tiles x 18
static constexpr int SEG_F2  = SEG_F3 + 126;  // 7 x 18
static constexpr int SEG_F1  = SEG_F2 + 486;  // 27 x 18
static constexpr int SEG_F0  = SEG_F1 + 1944; // 108 x 18
static constexpr int SEG_CT  = SEG_F0 + 576;  // convT2: 147456/256
static constexpr int SEG_SP  = SEG_CT + 486;  // sampos
static constexpr int PREP_GRID = SEG_SP;      // 3654

typedef __attribute__((ext_vector_type(8))) short short8;   // 8 bf16 (4 VGPRs)
typedef __attribute__((ext_vector_type(4))) float floatx4;

__device__ __forceinline__ float bf2f(unsigned short u) {
    union { unsigned int i; float f; } v; v.i = ((unsigned)u) << 16; return v.f;
}
__device__ __forceinline__ unsigned short f2bf_rne(float f) {
    union { float f; unsigned int i; } v; v.f = f;
    unsigned int u = v.i;
    u += 0x7fffu + ((u >> 16) & 1u);
    return (unsigned short)(u >> 16);
}
__device__ __forceinline__ short8 pack8(const float* t) {
    union { unsigned short u[8]; short8 s; } r;
    #pragma unroll
    for (int i = 0; i < 8; ++i) r.u[i] = f2bf_rne(t[i]);
    return r.s;
}

// ---------------- fused prep kernel ----------------
// blocks [0,SEG_F0): projection GEMMs via bf16 MFMA, A direct-to-register:
//      E_l[n,s,o] = sum_c f_l[n,c,s] * we_l[o,c]
//      tile M=64 (s; wave w owns 16 rows) x N=128 (o), BK=32 (zero-padded).
//      A-frag: 8 coalesced global dwords/lane (no LDS, no transpose).
//      B (we): per-ktile LDS stage [o][k], pad 40 (2-way banks = free).
// blocks [SEG_F0,SEG_CT): convT2[o*1152+(k2*128+c)] = bf16(conv_w[o*1152+c*9+k2])
// blocks [SEG_CT,SEG_SP): sampling positions
__global__ __launch_bounds__(256) void prep_k(
    const float* __restrict__ f0, const float* __restrict__ f1,
    const float* __restrict__ f2, const float* __restrict__ f3,
    const float* __restrict__ we0, const float* __restrict__ we1,
    const float* __restrict__ we2, const float* __restrict__ we3,
    const float* __restrict__ conv_w, unsigned short* __restrict__ convT2,
    const float* __restrict__ query, const float* __restrict__ value,
    const float* __restrict__ key,
    const float* __restrict__ w_off, const float* __restrict__ b_off,
    const float* __restrict__ w_attn, const float* __restrict__ b_attn,
    float* __restrict__ samp, unsigned short* __restrict__ Ebase)
{
    const int bid = blockIdx.x;
    const int tid = threadIdx.x;

    if (bid < SEG_F0) {
        __shared__ unsigned short Bs[128][40];   // [o][k], pad 32->40

        const float* A; const float* W; unsigned short* Eo;
        int M, K, m0;
        if (bid < SEG_F3) {
            int n = bid >> 1, t = bid & 1;
            M = 108; K = 384; A = f3 + (long)n * 384 * 108; W = we3;
            Eo = Ebase + E3_OFF + (long)n * 108 * 128; m0 = t * 64;
        } else if (bid < SEG_F2) {
            int r = bid - SEG_F3; int n = r / 7, t = r - n * 7;
            M = 432; K = 192; A = f2 + (long)n * 192 * 432; W = we2;
            Eo = Ebase + E2_OFF + (long)n * 432 * 128; m0 = t * 64;
        } else if (bid < SEG_F1) {
            int r = bid - SEG_F2; int n = r / 27, t = r - n * 27;
            M = 1728; K = 96; A = f1 + (long)n * 96 * 1728; W = we1;
            Eo = Ebase + E1_OFF + (long)n * 1728 * 128; m0 = t * 64;
        } else {
            int r = bid - SEG_F1; int n = r / 108, t = r - n * 108;
            M = 6912; K = 48; A = f0 + (long)n * 48 * 6912; W = we0;
            Eo = Ebase + E0_OFF + (long)n * 6912 * 128; m0 = t * 64;
        }

        const int lane = tid & 63;
        const int wave = tid >> 6;
        const int l15  = lane & 15;
        const int quad = lane >> 4;
        const int mg   = m0 + wave * 16 + l15;   // global m row for this lane

        floatx4 acc[8];
        #pragma unroll
        for (int j = 0; j < 8; ++j) acc[j] = (floatx4){0.f, 0.f, 0.f, 0.f};

        // B staging: thread -> o = tid>>1 (0..127), k-half = (tid&1)*16
        const int sbo = tid >> 1;
        const int sbk = (tid & 1) << 4;

        float4 bv0, bv1, bv2, bv3;
        auto fetchB = [&](int k0) {
            bv0 = (float4){0,0,0,0}; bv1 = bv0; bv2 = bv0; bv3 = bv0;
            if (k0 + sbk < K) {   // K%16==0
                const float* wp = W + (long)sbo * K + k0 + sbk;
                bv0 = *(const float4*)wp;
                bv1 = *(const float4*)(wp + 4);
                bv2 = *(const float4*)(wp + 8);
                bv3 = *(const float4*)(wp + 12);
            }
        };
        fetchB(0);

        for (int k0 = 0; k0 < K; k0 += 32) {
            // A direct loads (issued before barrier; independent of LDS)
            float a_f[8];
            {
                const int kq = k0 + quad * 8;
                const float* ap = A + (long)kq * M + mg;
                #pragma unroll
                for (int j = 0; j < 8; ++j) {
                    a_f[j] = 0.f;
                    if (mg < M && kq + j < K) a_f[j] = ap[(long)j * M];
                }
            }
            // B -> LDS
            {
                float tmp[16] = {bv0.x, bv0.y, bv0.z, bv0.w, bv1.x, bv1.y, bv1.z, bv1.w,
                                 bv2.x, bv2.y, bv2.z, bv2.w, bv3.x, bv3.y, bv3.z, bv3.w};
                unsigned short t[16];
                #pragma unroll
                for (int i = 0; i < 16; ++i) t[i] = f2bf_rne(tmp[i]);
                *(uint4*)&Bs[sbo][sbk]     = *(const uint4*)&t[0];
                *(uint4*)&Bs[sbo][sbk + 8] = *(const uint4*)&t[8];
            }
            __syncthreads();
            if (k0 + 32 < K) fetchB(k0 + 32);

            short8 af = pack8(a_f);
            #pragma unroll
            for (int nt = 0; nt < 8; ++nt) {
                short8 bf = *(const short8*)&Bs[nt * 16 + l15][quad * 8];
                acc[nt] = __builtin_amdgcn_mfma_f32_16x16x32_bf16(af, bf, acc[nt], 0, 0, 0);
            }
            __syncthreads();
        }

        // epilogue: C/D col=lane&15 (o), row=quad*4+r (m within the wave's 16)
        #pragma unroll
        for (int nt = 0; nt < 8; ++nt) {
            int col = nt * 16 + l15;
            #pragma unroll
            for (int r = 0; r < 4; ++r) {
                int m = m0 + wave * 16 + quad * 4 + r;
                if (m < M)
                    Eo[(long)m * 128 + col] = f2bf_rne(acc[nt][r]);
            }
        }
    } else if (bid < SEG_CT) {
        // ---- convT2 transpose+cast ----
        int idx = (bid - SEG_F0) * 256 + tid;
        if (idx < 147456) {
            int o = idx / 1152, kk = idx - o * 1152;
            int k2 = kk >> 7, c = kk & 127;
            convT2[idx] = f2bf_rne(conv_w[o * 1152 + c * 9 + k2]);
        }
    } else {
        // ---- sampling positions, one (b,t1) per block ----
        const int bt1 = bid - SEG_CT;      // 0..485
        const int b  = bt1 / 243, t1 = bt1 - b * 243;
        const int t2 = t1 / 27,  t3 = t1 - t2 * 27;
        const int n  = b * 9 + t2;
        __shared__ float logit[17][2];
        __shared__ float aw[17][2];

        if (tid < 34) {
            int p = tid >> 1, o = tid & 1;
            const float* vrow = value + ((long)bt1 * 17 + p) * 128;
            const float* wrow = w_attn + o * 128;
            float s = 0.f;
            for (int c = 0; c < 128; c += 4) {
                float4 v = *(const float4*)(vrow + c);
                float4 w = *(const float4*)(wrow + c);
                s += v.x * w.x + v.y * w.y + v.z * w.z + v.w * w.w;
            }
            logit[p][o] = s + b_attn[o];
        }
        __syncthreads();
        if (tid < 17) {
            float l0 = logit[tid][0], l1 = logit[tid][1];
            float mx = fmaxf(l0, l1);
            float e0 = expf(l0 - mx), e1 = expf(l1 - mx);
            float inv = 1.f / (e0 + e1);
            aw[tid][0] = e0 * inv; aw[tid][1] = e1 * inv;
        }
        __syncthreads();
        for (int j = tid; j < 306; j += 256) {
            int q = j >> 1, o = j & 1;
            const float* qrow = query + ((long)bt1 * 153 + q) * 128;
            const float* wrow = w_off + o * 128;
            float s = 0.f;
            for (int c = 0; c < 128; c += 4) {
                float4 v = *(const float4*)(qrow + c);
                float4 w = *(const float4*)(wrow + c);
                s += v.x * w.x + v.y * w.y + v.z * w.z + v.w * w.w;
            }
            float off = tanhf(s + b_off[o]);
            float sp = off * aw[q % 17][o];
            long kidx = (((long)n * 27 + t3) * 153 + q) * 2 + o;
            samp[kidx] = key[kidx] + sp;
        }
    }
}

// ---------------- fused gather + blend + conv kernel ----------------
// One block per (b,t1). 512 threads = 8 waves.
// Phase 1: gather 153 positions x 128 ch (16 pos-groups of 32 lanes),
//          write nq fp32 to global + bf16 row to LDS nqb[q][136pad].
// Phase 2: conv GEMM nv[p][o] = sum_{k2,c} nqb[p*9+k2][c]*convT2[o][k2*128+c]
//          + conv_b[o].  M=17 (2 tiles of 16), K=1152, 16x16x32 MFMA;
//          A from LDS (b128, 2-way banks), B direct from L2-hot convT2.
__global__ __launch_bounds__(512) void gc_k(
    const unsigned short* __restrict__ Ebase,
    const float* __restrict__ samp, const float* __restrict__ query,
    const float* __restrict__ be0, const float* __restrict__ be1,
    const float* __restrict__ be2, const float* __restrict__ be3,
    const unsigned short* __restrict__ convT2, const float* __restrict__ conv_b,
    float* __restrict__ nq, float* __restrict__ nv)
{
    __shared__ unsigned short nqb[153][136];   // bf16 new_query rows, pad 128->136

    const int tid = threadIdx.x;
    const int bt1 = blockIdx.x;                // 0..485
    const int b  = bt1 / 243, t1 = bt1 - b * 243;
    const int t2 = t1 / 27,  t3 = t1 - t2 * 27;
    const int n  = b * 9 + t2;

    // ---------- phase 1: gather ----------
    const int g  = tid >> 5;                   // pos-group 0..15
    const int c4 = (tid & 31) << 2;            // channel base
    const long Eoffs[4] = {E0_OFF, E1_OFF, E2_OFF, E3_OFF};
    const int Hs[4] = {96, 48, 24, 12}, Wd[4] = {72, 36, 18, 9};

    float bsx = be0[c4]     + be1[c4]     + be2[c4]     + be3[c4];
    float bsy = be0[c4 + 1] + be1[c4 + 1] + be2[c4 + 1] + be3[c4 + 1];
    float bsz = be0[c4 + 2] + be1[c4 + 2] + be2[c4 + 2] + be3[c4 + 2];
    float bsw = be0[c4 + 3] + be1[c4 + 3] + be2[c4 + 3] + be3[c4 + 3];

    for (int it = 0; it < 10; ++it) {
        const int q = it * 16 + g;
        if (q < 153) {
            const long sbase = (((long)n * 27 + t3) * 153 + q) * 2;
            const float gx = samp[sbase], gy = samp[sbase + 1];

            float ax = 0.f, ay = 0.f, az = 0.f, aww = 0.f;
            #pragma unroll
            for (int l = 0; l < 4; ++l) {
                const int H = Hs[l], W = Wd[l];
                const unsigned short* E = Ebase + Eoffs[l] + (long)n * H * W * 128 + c4;
                float ix = ((gx + 1.f) * (float)W - 1.f) * 0.5f;
                float iy = ((gy + 1.f) * (float)H - 1.f) * 0.5f;
                float fx0 = floorf(ix), fy0 = floorf(iy);
                int x0 = (int)fx0, y0 = (int)fy0;
                int x1 = x0 + 1, y1 = y0 + 1;
                float wx1 = ix - fx0, wx0 = 1.f - wx1;
                float wy1 = iy - fy0, wy0 = 1.f - wy1;
                float w00 = wy0 * wx0, w01 = wy0 * wx1, w10 = wy1 * wx0, w11 = wy1 * wx1;
                bool vy0 = (unsigned)y0 < (unsigned)H, vy1 = (unsigned)y1 < (unsigned)H;
                bool vx0 = (unsigned)x0 < (unsigned)W, vx1 = (unsigned)x1 < (unsigned)W;
                if (vy0 && vx0) { ushort4 v = *(const ushort4*)(E + ((long)y0 * W + x0) * 128);
                    ax = fmaf(w00, bf2f(v.x), ax); ay = fmaf(w00, bf2f(v.y), ay);
                    az = fmaf(w00, bf2f(v.z), az); aww = fmaf(w00, bf2f(v.w), aww); }
                if (vy0 && vx1) { ushort4 v = *(const ushort4*)(E + ((long)y0 * W + x1) * 128);
                    ax = fmaf(w01, bf2f(v.x), ax); ay = fmaf(w01, bf2f(v.y), ay);
                    az = fmaf(w01, bf2f(v.z), az); aww = fmaf(w01, bf2f(v.w), aww); }
                if (vy1 && vx0) { ushort4 v = *(const ushort4*)(E + ((long)y1 * W + x0) * 128);
                    ax = fmaf(w10, bf2f(v.x), ax); ay = fmaf(w10, bf2f(v.y), ay);
                    az = fmaf(w10, bf2f(v.z), az); aww = fmaf(w10, bf2f(v.w), aww); }
                if (vy1 && vx1) { ushort4 v = *(const ushort4*)(E + ((long)y1 * W + x1) * 128);
                    ax = fmaf(w11, bf2f(v.x), ax); ay = fmaf(w11, bf2f(v.y), ay);
                    az = fmaf(w11, bf2f(v.z), az); aww = fmaf(w11, bf2f(v.w), aww); }
            }
            float mx = 0.25f * (ax + bsx), my = 0.25f * (ay + bsy);
            float mz = 0.25f * (az + bsz), mw = 0.25f * (aww + bsw);
            const long qi = ((long)bt1 * 153 + q) * 128 + c4;
            float4 qv = *(const float4*)(query + qi);
            float4 o;
            o.x = 0.1f * mx + 0.9f * qv.x;
            o.y = 0.1f * my + 0.9f * qv.y;
            o.z = 0.1f * mz + 0.9f * qv.z;
            o.w = 0.1f * mw + 0.9f * qv.w;
            *(float4*)(nq + qi) = o;
            unsigned short t[4] = {f2bf_rne(o.x), f2bf_rne(o.y), f2bf_rne(o.z), f2bf_rne(o.w)};
            *(uint2*)&nqb[q][c4] = *(const uint2*)t;
        }
    }
    __syncthreads();

    // ---------- phase 2: conv GEMM ----------
    const int lane = tid & 63;
    const int wave = tid >> 6;        // 0..7
    const int mt   = wave >> 2;       // m-tile: p base 0 / 16
    const int n0   = (wave & 3) * 32; // 32-col slice
    const int l15  = lane & 15;
    const int quad = lane >> 4;

    floatx4 acc[2];
    acc[0] = (floatx4){0.f, 0.f, 0.f, 0.f};
    acc[1] = acc[0];

    const int p = mt * 16 + l15;
    for (int kt = 0; kt < 36; ++kt) {
        const int k0 = kt * 32;
        const int k2 = k0 >> 7;
        const int cb = (k0 & 127) + quad * 8;
        const int qq = (p < 17) ? (p * 9 + k2) : 0;
        short8 af = *(const short8*)&nqb[qq][cb];
        #pragma unroll
        for (int nt = 0; nt < 2; ++nt) {
            const int col = n0 + nt * 16 + l15;
            short8 bf = *(const short8*)(convT2 + (long)col * 1152 + k0 + quad * 8);
            acc[nt] = __builtin_amdgcn_mfma_f32_16x16x32_bf16(af, bf, acc[nt], 0, 0, 0);
        }
    }

    #pragma unroll
    for (int nt = 0; nt < 2; ++nt) {
        const int col = n0 + nt * 16 + l15;
        const float bias = conv_b[col];
        #pragma unroll
        for (int r = 0; r < 4; ++r) {
            const int pr = mt * 16 + quad * 4 + r;
            if (pr < 17)
                nv[((long)bt1 * 17 + pr) * 128 + col] = acc[nt][r] + bias;
        }
    }
}

extern "C" void kernel_launch(void* const* d_in, const int* in_sizes, int n_in,
                              void* d_out, int out_size, void* d_ws, size_t ws_size,
                              hipStream_t stream) {
    const float* f0     = (const float*)d_in[0];
    const float* f1     = (const float*)d_in[1];
    const float* f2     = (const float*)d_in[2];
    const float* f3     = (const float*)d_in[3];
    const float* query  = (const float*)d_in[4];
    const float* key    = (const float*)d_in[5];
    const float* value  = (const float*)d_in[6];
    const float* w_off  = (const float*)d_in[7];
    const float* b_off  = (const float*)d_in[8];
    const float* w_attn = (const float*)d_in[9];
    const float* b_attn = (const float*)d_in[10];
    const float* we0    = (const float*)d_in[11];
    const float* be0    = (const float*)d_in[12];
    const float* we1    = (const float*)d_in[13];
    const float* be1    = (const float*)d_in[14];
    const float* we2    = (const float*)d_in[15];
    const float* be2    = (const float*)d_in[16];
    const float* we3    = (const float*)d_in[17];
    const float* be3    = (const float*)d_in[18];
    const float* conv_w = (const float*)d_in[19];
    const float* conv_b = (const float*)d_in[20];

    float* out  = (float*)d_out;
    float* nq   = out;                       // new_query
    float* nv   = out + NQ_SIZE;             // new_value
    float* samp = out + NQ_SIZE + NV_SIZE;   // sampling_positions

    // ws layout: E maps (bf16, 21,150,720) | convT2 (bf16, 147,456)
    unsigned short* Ebase  = (unsigned short*)d_ws;
    unsigned short* convT2 = Ebase + E_END;

    // 1. fused prep: projections (MFMA, A-direct) + convT2 + sampling positions
    prep_k<<<PREP_GRID, 256, 0, stream>>>(
        f0, f1, f2, f3, we0, we1, we2, we3, conv_w, convT2,
        query, value, key, w_off, b_off, w_attn, b_attn, samp, Ebase);

    // 2. fused gather + blend + conv: one block per (b,t1)
    gc_k<<<486, 512, 0, stream>>>(Ebase, samp, query, be0, be1, be2, be3,
                                  convT2, conv_b, nq, nv);
}

// Round 6
// 243.036 us; speedup vs baseline: 1.1506x; 1.1506x over previous
//
#include <hip/hip_runtime.h>
#include <hip/hip_bf16.h>

// ---------------- problem constants ----------------
// B=2 T2=9 T3=27 T1=243 P=17 K2=9 C=128
// CH = {48,96,192,384}, HW = {(96,72),(48,36),(24,18),(12,9)}, N=18
static constexpr int NQ_SIZE = 9517824;
static constexpr int NV_SIZE = 1057536;
static constexpr int NPOS    = 74358;   // 486*153 sampling points
static constexpr int M_CONV  = 8262;    // 2*243*17 rows of the conv GEMM

// E-map (projected feature, bf16, channels-last [n,h,w,128]) element offsets in ws
static constexpr long E0_OFF = 0;
static constexpr long E1_OFF = 15925248;            // 18*96*72*128
static constexpr long E2_OFF = E1_OFF + 3981312;    // 18*48*36*128
static constexpr long E3_OFF = E2_OFF + 995328;     // 18*24*18*128
static constexpr long E_END  = E3_OFF + 248832;     // 18*12*9*128  -> 21,150,720 elems

// prep kernel block-range segmentation (long-serial levels first)
static constexpr int SEG_F3  = 36;            // 2 tiles x 18
static constexpr int SEG_F2  = SEG_F3 + 126;  // 7 x 18
static constexpr int SEG_F1  = SEG_F2 + 486;  // 27 x 18
static constexpr int SEG_F0  = SEG_F1 + 1944; // 108 x 18
static constexpr int SEG_CT  = SEG_F0 + 576;  // convT2: 147456/256
static constexpr int SEG_SP  = SEG_CT + 486;  // sampos
static constexpr int PREP_GRID = SEG_SP;      // 3654

typedef __attribute__((ext_vector_type(8))) short short8;   // 8 bf16 (4 VGPRs)
typedef __attribute__((ext_vector_type(4))) float floatx4;

__device__ __forceinline__ float bf2f(unsigned short u) {
    union { unsigned int i; float f; } v; v.i = ((unsigned)u) << 16; return v.f;
}
__device__ __forceinline__ unsigned short f2bf_rne(float f) {
    union { float f; unsigned int i; } v; v.f = f;
    unsigned int u = v.i;
    u += 0x7fffu + ((u >> 16) & 1u);
    return (unsigned short)(u >> 16);
}
__device__ __forceinline__ short8 pack8(const float* t) {
    union { unsigned short u[8]; short8 s; } r;
    #pragma unroll
    for (int i = 0; i < 8; ++i) r.u[i] = f2bf_rne(t[i]);
    return r.s;
}

// ---------------- fused prep kernel ----------------
// blocks [0,SEG_F0): projection GEMMs via bf16 MFMA, A direct-to-register:
//      E_l[n,s,o] = sum_c f_l[n,c,s] * we_l[o,c]
//      tile M=64 (s; wave w owns 16 rows) x N=128 (o), BK=32 (zero-padded).
//      A-frag: 8 coalesced global dwords/lane (no LDS, no transpose).
//      B (we): per-ktile LDS stage [o][k], pad 40 (2-way banks = free).
// blocks [SEG_F0,SEG_CT): convT2[o*1152+(k2*128+c)] = bf16(conv_w[o*1152+c*9+k2])
// blocks [SEG_CT,SEG_SP): sampling positions
__global__ __launch_bounds__(256) void prep_k(
    const float* __restrict__ f0, const float* __restrict__ f1,
    const float* __restrict__ f2, const float* __restrict__ f3,
    const float* __restrict__ we0, const float* __restrict__ we1,
    const float* __restrict__ we2, const float* __restrict__ we3,
    const float* __restrict__ conv_w, unsigned short* __restrict__ convT2,
    const float* __restrict__ query, const float* __restrict__ value,
    const float* __restrict__ key,
    const float* __restrict__ w_off, const float* __restrict__ b_off,
    const float* __restrict__ w_attn, const float* __restrict__ b_attn,
    float* __restrict__ samp, unsigned short* __restrict__ Ebase)
{
    const int bid = blockIdx.x;
    const int tid = threadIdx.x;

    if (bid < SEG_F0) {
        __shared__ unsigned short Bs[128][40];   // [o][k], pad 32->40

        const float* A; const float* W; unsigned short* Eo;
        int M, K, m0;
        if (bid < SEG_F3) {
            int n = bid >> 1, t = bid & 1;
            M = 108; K = 384; A = f3 + (long)n * 384 * 108; W = we3;
            Eo = Ebase + E3_OFF + (long)n * 108 * 128; m0 = t * 64;
        } else if (bid < SEG_F2) {
            int r = bid - SEG_F3; int n = r / 7, t = r - n * 7;
            M = 432; K = 192; A = f2 + (long)n * 192 * 432; W = we2;
            Eo = Ebase + E2_OFF + (long)n * 432 * 128; m0 = t * 64;
        } else if (bid < SEG_F1) {
            int r = bid - SEG_F2; int n = r / 27, t = r - n * 27;
            M = 1728; K = 96; A = f1 + (long)n * 96 * 1728; W = we1;
            Eo = Ebase + E1_OFF + (long)n * 1728 * 128; m0 = t * 64;
        } else {
            int r = bid - SEG_F1; int n = r / 108, t = r - n * 108;
            M = 6912; K = 48; A = f0 + (long)n * 48 * 6912; W = we0;
            Eo = Ebase + E0_OFF + (long)n * 6912 * 128; m0 = t * 64;
        }

        const int lane = tid & 63;
        const int wave = tid >> 6;
        const int l15  = lane & 15;
        const int quad = lane >> 4;
        const int mg   = m0 + wave * 16 + l15;   // global m row for this lane

        floatx4 acc[8];
        #pragma unroll
        for (int j = 0; j < 8; ++j) acc[j] = (floatx4){0.f, 0.f, 0.f, 0.f};

        // B staging: thread -> o = tid>>1 (0..127), k-half = (tid&1)*16
        const int sbo = tid >> 1;
        const int sbk = (tid & 1) << 4;

        float4 bv0, bv1, bv2, bv3;
        auto fetchB = [&](int k0) {
            bv0 = (float4){0,0,0,0}; bv1 = bv0; bv2 = bv0; bv3 = bv0;
            if (k0 + sbk < K) {   // K%16==0
                const float* wp = W + (long)sbo * K + k0 + sbk;
                bv0 = *(const float4*)wp;
                bv1 = *(const float4*)(wp + 4);
                bv2 = *(const float4*)(wp + 8);
                bv3 = *(const float4*)(wp + 12);
            }
        };
        fetchB(0);

        for (int k0 = 0; k0 < K; k0 += 32) {
            // A direct loads (issued before barrier; independent of LDS)
            float a_f[8];
            {
                const int kq = k0 + quad * 8;
                const float* ap = A + (long)kq * M + mg;
                #pragma unroll
                for (int j = 0; j < 8; ++j) {
                    a_f[j] = 0.f;
                    if (mg < M && kq + j < K) a_f[j] = ap[(long)j * M];
                }
            }
            // B -> LDS
            {
                float tmp[16] = {bv0.x, bv0.y, bv0.z, bv0.w, bv1.x, bv1.y, bv1.z, bv1.w,
                                 bv2.x, bv2.y, bv2.z, bv2.w, bv3.x, bv3.y, bv3.z, bv3.w};
                unsigned short t[16];
                #pragma unroll
                for (int i = 0; i < 16; ++i) t[i] = f2bf_rne(tmp[i]);
                *(uint4*)&Bs[sbo][sbk]     = *(const uint4*)&t[0];
                *(uint4*)&Bs[sbo][sbk + 8] = *(const uint4*)&t[8];
            }
            __syncthreads();
            if (k0 + 32 < K) fetchB(k0 + 32);

            short8 af = pack8(a_f);
            #pragma unroll
            for (int nt = 0; nt < 8; ++nt) {
                short8 bf = *(const short8*)&Bs[nt * 16 + l15][quad * 8];
                acc[nt] = __builtin_amdgcn_mfma_f32_16x16x32_bf16(af, bf, acc[nt], 0, 0, 0);
            }
            __syncthreads();
        }

        // epilogue: C/D col=lane&15 (o), row=quad*4+r (m within the wave's 16)
        #pragma unroll
        for (int nt = 0; nt < 8; ++nt) {
            int col = nt * 16 + l15;
            #pragma unroll
            for (int r = 0; r < 4; ++r) {
                int m = m0 + wave * 16 + quad * 4 + r;
                if (m < M)
                    Eo[(long)m * 128 + col] = f2bf_rne(acc[nt][r]);
            }
        }
    } else if (bid < SEG_CT) {
        // ---- convT2 transpose+cast ----
        int idx = (bid - SEG_F0) * 256 + tid;
        if (idx < 147456) {
            int o = idx / 1152, kk = idx - o * 1152;
            int k2 = kk >> 7, c = kk & 127;
            convT2[idx] = f2bf_rne(conv_w[o * 1152 + c * 9 + k2]);
        }
    } else {
        // ---- sampling positions, one (b,t1) per block ----
        const int bt1 = bid - SEG_CT;      // 0..485
        const int b  = bt1 / 243, t1 = bt1 - b * 243;
        const int t2 = t1 / 27,  t3 = t1 - t2 * 27;
        const int n  = b * 9 + t2;
        __shared__ float logit[17][2];
        __shared__ float aw[17][2];

        if (tid < 34) {
            int p = tid >> 1, o = tid & 1;
            const float* vrow = value + ((long)bt1 * 17 + p) * 128;
            const float* wrow = w_attn + o * 128;
            float s = 0.f;
            for (int c = 0; c < 128; c += 4) {
                float4 v = *(const float4*)(vrow + c);
                float4 w = *(const float4*)(wrow + c);
                s += v.x * w.x + v.y * w.y + v.z * w.z + v.w * w.w;
            }
            logit[p][o] = s + b_attn[o];
        }
        __syncthreads();
        if (tid < 17) {
            float l0 = logit[tid][0], l1 = logit[tid][1];
            float mx = fmaxf(l0, l1);
            float e0 = expf(l0 - mx), e1 = expf(l1 - mx);
            float inv = 1.f / (e0 + e1);
            aw[tid][0] = e0 * inv; aw[tid][1] = e1 * inv;
        }
        __syncthreads();
        for (int j = tid; j < 306; j += 256) {
            int q = j >> 1, o = j & 1;
            const float* qrow = query + ((long)bt1 * 153 + q) * 128;
            const float* wrow = w_off + o * 128;
            float s = 0.f;
            for (int c = 0; c < 128; c += 4) {
                float4 v = *(const float4*)(qrow + c);
                float4 w = *(const float4*)(wrow + c);
                s += v.x * w.x + v.y * w.y + v.z * w.z + v.w * w.w;
            }
            float off = tanhf(s + b_off[o]);
            float sp = off * aw[q % 17][o];
            long kidx = (((long)n * 27 + t3) * 153 + q) * 2 + o;
            samp[kidx] = key[kidx] + sp;
        }
    }
}

// ---------------- gather + mean + blend -> new_query ----------------
// 8 positions/block, 32 lanes/position, 4 channels/lane (float4).
__global__ __launch_bounds__(256) void gather_k(
    const unsigned short* __restrict__ Ebase,
    const float* __restrict__ samp, const float* __restrict__ query,
    const float* __restrict__ be0, const float* __restrict__ be1,
    const float* __restrict__ be2, const float* __restrict__ be3,
    float* __restrict__ nq)
{
    const int tid = threadIdx.x;
    const int pos = blockIdx.x * 8 + (tid >> 5);
    if (pos >= NPOS) return;
    const int c4 = (tid & 31) << 2;
    const int bt1 = pos / 153, q = pos - bt1 * 153;
    const int b  = bt1 / 243, t1 = bt1 - b * 243;
    const int t2 = t1 / 27,  t3 = t1 - t2 * 27;
    const int n  = b * 9 + t2;
    const long sbase = (((long)n * 27 + t3) * 153 + q) * 2;
    const float gx = samp[sbase], gy = samp[sbase + 1];

    float ax = 0.f, ay = 0.f, az = 0.f, aww = 0.f;
    const long Eoffs[4] = {E0_OFF, E1_OFF, E2_OFF, E3_OFF};
    const int Hs[4] = {96, 48, 24, 12}, Wd[4] = {72, 36, 18, 9};
    #pragma unroll
    for (int l = 0; l < 4; ++l) {
        const int H = Hs[l], W = Wd[l];
        const unsigned short* E = Ebase + Eoffs[l] + (long)n * H * W * 128 + c4;
        float ix = ((gx + 1.f) * (float)W - 1.f) * 0.5f;
        float iy = ((gy + 1.f) * (float)H - 1.f) * 0.5f;
        float fx0 = floorf(ix), fy0 = floorf(iy);
        int x0 = (int)fx0, y0 = (int)fy0;
        int x1 = x0 + 1, y1 = y0 + 1;
        float wx1 = ix - fx0, wx0 = 1.f - wx1;
        float wy1 = iy - fy0, wy0 = 1.f - wy1;
        float w00 = wy0 * wx0, w01 = wy0 * wx1, w10 = wy1 * wx0, w11 = wy1 * wx1;
        bool vy0 = (unsigned)y0 < (unsigned)H, vy1 = (unsigned)y1 < (unsigned)H;
        bool vx0 = (unsigned)x0 < (unsigned)W, vx1 = (unsigned)x1 < (unsigned)W;
        if (vy0 && vx0) { ushort4 v = *(const ushort4*)(E + ((long)y0 * W + x0) * 128);
            ax = fmaf(w00, bf2f(v.x), ax); ay = fmaf(w00, bf2f(v.y), ay);
            az = fmaf(w00, bf2f(v.z), az); aww = fmaf(w00, bf2f(v.w), aww); }
        if (vy0 && vx1) { ushort4 v = *(const ushort4*)(E + ((long)y0 * W + x1) * 128);
            ax = fmaf(w01, bf2f(v.x), ax); ay = fmaf(w01, bf2f(v.y), ay);
            az = fmaf(w01, bf2f(v.z), az); aww = fmaf(w01, bf2f(v.w), aww); }
        if (vy1 && vx0) { ushort4 v = *(const ushort4*)(E + ((long)y1 * W + x0) * 128);
            ax = fmaf(w10, bf2f(v.x), ax); ay = fmaf(w10, bf2f(v.y), ay);
            az = fmaf(w10, bf2f(v.z), az); aww = fmaf(w10, bf2f(v.w), aww); }
        if (vy1 && vx1) { ushort4 v = *(const ushort4*)(E + ((long)y1 * W + x1) * 128);
            ax = fmaf(w11, bf2f(v.x), ax); ay = fmaf(w11, bf2f(v.y), ay);
            az = fmaf(w11, bf2f(v.z), az); aww = fmaf(w11, bf2f(v.w), aww); }
    }
    float bsx = be0[c4]     + be1[c4]     + be2[c4]     + be3[c4];
    float bsy = be0[c4 + 1] + be1[c4 + 1] + be2[c4 + 1] + be3[c4 + 1];
    float bsz = be0[c4 + 2] + be1[c4 + 2] + be2[c4 + 2] + be3[c4 + 2];
    float bsw = be0[c4 + 3] + be1[c4 + 3] + be2[c4 + 3] + be3[c4 + 3];
    float mx = 0.25f * (ax + bsx), my = 0.25f * (ay + bsy);
    float mz = 0.25f * (az + bsz), mw = 0.25f * (aww + bsw);
    const long qi = ((long)bt1 * 153 + q) * 128 + c4;
    float4 qv = *(const float4*)(query + qi);
    float4 o;
    o.x = 0.1f * mx + 0.9f * qv.x;
    o.y = 0.1f * my + 0.9f * qv.y;
    o.z = 0.1f * mz + 0.9f * qv.z;
    o.w = 0.1f * mw + 0.9f * qv.w;
    *(float4*)(nq + qi) = o;
}

// ---------------- conv GEMM via bf16 MFMA ----------------
// nv[m][o] = sum_kk nq[m*1152+kk] * convT2[o][kk] + conv_b[o]
// grid (259 m-tiles, 2 n-tiles); block 256 = 4 waves (2x2);
// tile M=32 x N=64, BK=32; register double-buffer. 518 blocks for latency hiding.
__global__ __launch_bounds__(256) void conv_mfma_k(
    const float* __restrict__ nq, const unsigned short* __restrict__ convT2,
    const float* __restrict__ conv_b, float* __restrict__ nv)
{
    __shared__ unsigned short As[32][40];   // [m][k] pad 32->40
    __shared__ unsigned short Bs[64][40];   // [n][k]

    const int tid  = threadIdx.x;
    const int lane = tid & 63;
    const int wave = tid >> 6;
    const int wm = (wave & 1) * 16;
    const int wn = (wave >> 1) * 32;
    const int m0 = blockIdx.x * 32;
    const int n0 = blockIdx.y * 64;
    const int l15  = lane & 15;
    const int quad = lane >> 4;

    floatx4 acc[2];
    acc[0] = (floatx4){0.f, 0.f, 0.f, 0.f};
    acc[1] = acc[0];

    const int am = tid >> 3;             // 0..31
    const int ak = (tid & 7) << 2;       // 0,4,..,28
    const int bn = tid >> 2;             // 0..63
    const int bk = (tid & 3) << 3;       // 0,8,16,24

    float4 a0; uint4 bv;
    auto fetch = [&](int k0) {
        a0 = (float4){0,0,0,0};
        int row = m0 + am;
        if (row < M_CONV)
            a0 = *(const float4*)(nq + (long)row * 1152 + k0 + ak);
        bv = *(const uint4*)(convT2 + (long)(n0 + bn) * 1152 + k0 + bk);
    };
    fetch(0);

    for (int k0 = 0; k0 < 1152; k0 += 32) {
        unsigned short t[4] = {f2bf_rne(a0.x), f2bf_rne(a0.y), f2bf_rne(a0.z), f2bf_rne(a0.w)};
        *(uint2*)&As[am][ak] = *(const uint2*)t;
        *(uint4*)&Bs[bn][bk] = bv;
        __syncthreads();
        if (k0 + 32 < 1152) fetch(k0 + 32);

        short8 af = *(const short8*)&As[wm + l15][quad * 8];
        #pragma unroll
        for (int nt = 0; nt < 2; ++nt) {
            short8 bf = *(const short8*)&Bs[wn + nt * 16 + l15][quad * 8];
            acc[nt] = __builtin_amdgcn_mfma_f32_16x16x32_bf16(af, bf, acc[nt], 0, 0, 0);
        }
        __syncthreads();
    }

    // epilogue: C/D layout col=lane&15, row=quad*4+r
    #pragma unroll
    for (int nt = 0; nt < 2; ++nt) {
        int col = n0 + wn + nt * 16 + l15;
        float bias = conv_b[col];
        #pragma unroll
        for (int r = 0; r < 4; ++r) {
            int row = m0 + wm + quad * 4 + r;
            if (row < M_CONV)
                nv[(long)row * 128 + col] = acc[nt][r] + bias;
        }
    }
}

extern "C" void kernel_launch(void* const* d_in, const int* in_sizes, int n_in,
                              void* d_out, int out_size, void* d_ws, size_t ws_size,
                              hipStream_t stream) {
    const float* f0     = (const float*)d_in[0];
    const float* f1     = (const float*)d_in[1];
    const float* f2     = (const float*)d_in[2];
    const float* f3     = (const float*)d_in[3];
    const float* query  = (const float*)d_in[4];
    const float* key    = (const float*)d_in[5];
    const float* value  = (const float*)d_in[6];
    const float* w_off  = (const float*)d_in[7];
    const float* b_off  = (const float*)d_in[8];
    const float* w_attn = (const float*)d_in[9];
    const float* b_attn = (const float*)d_in[10];
    const float* we0    = (const float*)d_in[11];
    const float* be0    = (const float*)d_in[12];
    const float* we1    = (const float*)d_in[13];
    const float* be1    = (const float*)d_in[14];
    const float* we2    = (const float*)d_in[15];
    const float* be2    = (const float*)d_in[16];
    const float* we3    = (const float*)d_in[17];
    const float* be3    = (const float*)d_in[18];
    const float* conv_w = (const float*)d_in[19];
    const float* conv_b = (const float*)d_in[20];

    float* out  = (float*)d_out;
    float* nq   = out;                       // new_query
    float* nv   = out + NQ_SIZE;             // new_value
    float* samp = out + NQ_SIZE + NV_SIZE;   // sampling_positions

    // ws layout: E maps (bf16, 21,150,720) | convT2 (bf16, 147,456)
    unsigned short* Ebase  = (unsigned short*)d_ws;
    unsigned short* convT2 = Ebase + E_END;

    // 1. fused prep: projections (MFMA, A-direct) + convT2 + sampling positions
    prep_k<<<PREP_GRID, 256, 0, stream>>>(
        f0, f1, f2, f3, we0, we1, we2, we3, conv_w, convT2,
        query, value, key, w_off, b_off, w_attn, b_attn, samp, Ebase);

    // 2. gather + mean + blend -> new_query (9295 blocks)
    gather_k<<<(NPOS + 7) / 8, 256, 0, stream>>>(Ebase, samp, query, be0, be1, be2, be3, nq);

    // 3. new_value GEMM via MFMA: M=8262, K=1152, N=128 (518 blocks)
    conv_mfma_k<<<dim3(259, 2), 256, 0, stream>>>(nq, convT2, conv_b, nv);
}